// Round 9
// baseline (181.206 us; speedup 1.0000x reference)
//
#include <hip/hip_runtime.h>
#include <hip/hip_cooperative_groups.h>

#define N_ 512
#define D_ 128
#define LOG2E 1.44269504088896f

namespace cg = cooperative_groups;

// ws: [0, 8 MB)        xp_t f16 TRANSPOSED [inst][f=128][s=512]      (8,388,608 B)
//     [8, 8.5 MB)      sgEs u32 [inst][h=8][sp=256]  (Es pairs f16)  (  524,288 B)
//     [8.5, 9 MB)      sgFs u32 [inst][h=8][sp=256]  (Fs pairs f16)  (  524,288 B)
//     [9, 11 MB)       sgD float2 [inst][h=8][s=512] (Ed, Fd fp32)   (2,097,152 B)
//     [11, 13 MB)      mgT u32 [inst][q=4][dst=512][jw=4]            (2,097,152 B)
// R9: ONE cooperative kernel (256 blocks x 1024 thr = 1 block/CU).
// Phase 1: block (xcd=bid&7) produces xpt/sgE/F/D/mgT for insts
// 8xcd..8xcd+7 (proj via MFMA + va-scores; maskprep with NONTEMPORAL A
// loads so the 67MB stream doesn't evict produced data). grid.sync().
// Phase 2: same XCD consumes exactly that set (R8 attn+combine body,
// stagger + depth-4 ring kept). No kernel boundary -> no L2 invalidation
// between produce and consume; dataflow is same-XCD by construction,
// correctness guaranteed by grid.sync regardless of XCD mapping.

typedef __attribute__((ext_vector_type(8))) short short8;
typedef __attribute__((ext_vector_type(4))) float floatx4;
typedef __attribute__((ext_vector_type(4))) unsigned int uintx4;
typedef __attribute__((ext_vector_type(2))) _Float16 half2v;
typedef __attribute__((ext_vector_type(8))) _Float16 half8;

#if defined(__has_builtin)
#if __has_builtin(__builtin_amdgcn_exp2f)
#define EXP2F(x) __builtin_amdgcn_exp2f(x)
#else
#define EXP2F(x) exp2f(x)
#endif
#else
#define EXP2F(x) exp2f(x)
#endif

__device__ __forceinline__ unsigned int pkh(float a, float b) {
    auto h = __builtin_amdgcn_cvt_pkrtz(a, b);
    return __builtin_bit_cast(unsigned int, h);
}

__global__ __launch_bounds__(1024, 4) void fused_kernel(
    const float* __restrict__ x, const float* __restrict__ W,
    const float* __restrict__ pb, const float* __restrict__ att_src,
    const float* __restrict__ att_dst, const int* __restrict__ A,
    const float* __restrict__ bias,
    unsigned short* __restrict__ xpt, unsigned int* __restrict__ sgEs,
    unsigned int* __restrict__ sgFs, float2* __restrict__ sgD,
    unsigned int* __restrict__ mgT, float* __restrict__ hout)
{
    __shared__ unsigned int smem[16384];    // 64 KB, phase-aliased

    const int bid = blockIdx.x;
    const int xcd = bid & 7;
    const int idx = bid >> 3;               // 0..31 within XCD
    const int t = threadIdx.x;

    // ==================== PHASE 1: proj + scores + maskprep ====================
    {
        const int inst = xcd * 8 + (idx >> 2);   // this block's inst
        const int quarter = idx & 3;
        const int j = inst & 1;
        const int bi = inst >> 1;
        const int ij = (bi & 1) * 2 + j;
        const float* wb = W + (size_t)ij * D_ * D_;

        _Float16* va = (_Float16*)smem;          // [2][8][136] = 4352 B
        float* c0s = (float*)(smem + 1100);      // [2][8]

        // --- va build: t<512 covers both halves x 8 c x 32 k-groups ---
        if (t < 512) {
            const int halfv = t >> 8;
            const int c = (t >> 5) & 7;
            const int k0 = (t & 31) * 4;
            const int hn = halfv * 4 + (c & 3);
            const float* av = ((c < 4) ? att_src : att_dst) + ij * D_ + hn * 16;
            const float* Wh = wb + (size_t)(hn * 16) * D_ + k0;
            float a0 = 0.f, a1 = 0.f, a2 = 0.f, a3 = 0.f;
#pragma unroll
            for (int dd = 0; dd < 16; ++dd) {
                const float a = av[dd];
                const float4 wv = *(const float4*)(Wh + (size_t)dd * D_);
                a0 += wv.x * a; a1 += wv.y * a; a2 += wv.z * a; a3 += wv.w * a;
            }
            _Float16* vp = va + (halfv * 8 + c) * 136 + k0;
            vp[0] = (_Float16)(a0 * LOG2E);
            vp[1] = (_Float16)(a1 * LOG2E);
            vp[2] = (_Float16)(a2 * LOG2E);
            vp[3] = (_Float16)(a3 * LOG2E);
        }
        if (t < 16) {
            const int halfv = t >> 3;
            const int cc = t & 7;
            const int hn2 = halfv * 4 + (cc & 3);
            const float* av2 = ((cc < 4) ? att_src : att_dst) + ij * D_ + hn2 * 16;
            const float* pbp = pb + ij * D_ + hn2 * 16;
            float s = 0.f;
#pragma unroll
            for (int dd = 0; dd < 16; ++dd) s += pbp[dd] * av2[dd];
            c0s[halfv * 8 + cc] = s * LOG2E;
        }

        // --- proj: 4 sub-units of 256 thr: (ntile = q*2+(sub>>1), half = sub&1)
        const int sub = t >> 8;
        const int ntile = quarter * 2 + (sub >> 1);
        const int halfp = sub & 1;
        const int wavep = (t >> 6) & 3;
        const int L = t & 63, n = L & 15, q = L >> 4;
        const int n0w = ntile * 64 + wavep * 16;

        const float* xrow = x + ((size_t)bi * N_ + n0w + n) * D_ + q * 8;
        half8 Af[4];
#pragma unroll
        for (int kc = 0; kc < 4; ++kc) {
            const float4 a0 = *(const float4*)(xrow + kc * 32);
            const float4 a1 = *(const float4*)(xrow + kc * 32 + 4);
            uintx4 au;
            au.x = pkh(a0.x, a0.y);
            au.y = pkh(a0.z, a0.w);
            au.z = pkh(a1.x, a1.y);
            au.w = pkh(a1.z, a1.w);
            Af[kc] = __builtin_bit_cast(half8, au);
        }

        __syncthreads();   // va_l ready

        // scores via MFMA: S[reg] = score[node n0w+q*4+reg][c=n]
        floatx4 S = (floatx4){0.f, 0.f, 0.f, 0.f};
        {
            const _Float16* var = va + (halfp * 8 + (n & 7)) * 136 + q * 8;
#pragma unroll
            for (int kc = 0; kc < 4; ++kc) {
                const half8 Bs = *(const half8*)(var + kc * 32);
                S = __builtin_amdgcn_mfma_f32_16x16x32_f16(Af[kc], Bs, S, 0, 0, 0);
            }
        }

        // xp tiles
#pragma unroll
        for (int ft = 0; ft < 4; ++ft) {
            const int head = halfp * 4 + ft;
            const int fg = head * 16 + n;
            const float* wrow = wb + (size_t)fg * D_ + q * 8;
            floatx4 C = (floatx4){0.f, 0.f, 0.f, 0.f};
#pragma unroll
            for (int kc = 0; kc < 4; ++kc) {
                const float4 b0 = *(const float4*)(wrow + kc * 32);
                const float4 b1 = *(const float4*)(wrow + kc * 32 + 4);
                uintx4 bu;
                bu.x = pkh(b0.x, b0.y);
                bu.y = pkh(b0.z, b0.w);
                bu.z = pkh(b1.x, b1.y);
                bu.w = pkh(b1.z, b1.w);
                C = __builtin_amdgcn_mfma_f32_16x16x32_f16(
                    Af[kc], __builtin_bit_cast(half8, bu), C, 0, 0, 0);
            }
            const float pbv = pb[ij * D_ + fg];
            uint2 pk;
            pk.x = pkh(C[0] + pbv, C[1] + pbv);
            pk.y = pkh(C[2] + pbv, C[3] + pbv);
            *(uint2*)&xpt[((size_t)inst * D_ + fg) * N_ + n0w + q * 4] = pk;
        }

        // score epilogue: lanes n<4 -> Es/Fs, lanes 8..11 -> Ed/Fd
        if (n < 8) {
            const float cc2 = c0s[halfp * 8 + n];
            const float v0 = S[0] + cc2, v1 = S[1] + cc2;
            const float v2 = S[2] + cc2, v3 = S[3] + cc2;
            if (n < 4) {
                const int head = halfp * 4 + n;
                const size_t base = ((size_t)inst * 8 + head) * 256 + (n0w >> 1) + q * 2;
                sgEs[base + 0] = pkh(EXP2F(v0), EXP2F(v1));
                sgEs[base + 1] = pkh(EXP2F(v2), EXP2F(v3));
                sgFs[base + 0] = pkh(EXP2F(0.2f * v0), EXP2F(0.2f * v1));
                sgFs[base + 1] = pkh(EXP2F(0.2f * v2), EXP2F(0.2f * v3));
            } else {
                const int head = halfp * 4 + (n - 4);
                const size_t base = ((size_t)inst * 8 + head) * N_ + n0w + q * 4;
                float2 e0; e0.x = EXP2F(v0); e0.y = EXP2F(0.2f * v0); sgD[base + 0] = e0;
                float2 e1; e1.x = EXP2F(v1); e1.y = EXP2F(0.2f * v1); sgD[base + 1] = e1;
                float2 e2; e2.x = EXP2F(v2); e2.y = EXP2F(0.2f * v2); sgD[base + 2] = e2;
                float2 e3; e3.x = EXP2F(v3); e3.y = EXP2F(0.2f * v3); sgD[base + 3] = e3;
            }
        }

        // --- maskprep: t<512 does 2 old units; NONTEMPORAL A loads ---
        if (t < 512) {
            const int sub2 = t >> 8;
            const int u = idx * 2 + sub2;            // 0..63 per XCD
            const int bim = xcd * 4 + (u >> 4);      // (b,io) pair in XCD's set
            const int rem = u & 15;
            const int dg = rem >> 2, jw = rem & 3;
            const int tl = t & 255;
            const int qm = tl >> 6, dp = tl & 63;
            const int dstb = dg * 128 + dp * 2;
            const int sbase = jw * 128 + qm * 8;
            const long long* Ab =
                (const long long*)(A + (size_t)bim * N_ * N_ + dstb);
            unsigned int a00 = 0, a01 = 0, a10 = 0, a11 = 0;
#pragma unroll
            for (int cp = 0; cp < 4; ++cp) {
#pragma unroll
                for (int i = 0; i < 8; ++i) {
                    const int s = sbase + cp * 32 + i;
                    const long long vv =
                        __builtin_nontemporal_load(Ab + (size_t)s * (N_ / 2));
                    const unsigned int vx = (unsigned int)(vv & 0xffffffffll);
                    const unsigned int vy = (unsigned int)(vv >> 32);
                    const int bitp = cp * 8 + i;
                    a00 |= ((0x14u >> vx) & 1u) << bitp;   // val in {2,4}
                    a10 |= ((0x18u >> vx) & 1u) << bitp;   // val in {3,4}
                    a01 |= ((0x14u >> vy) & 1u) << bitp;
                    a11 |= ((0x18u >> vy) & 1u) << bitp;
                }
            }
            const int i0 = bim * 2;
            mgT[(((size_t)i0 * 4 + qm) * 512 + dstb + 0) * 4 + jw] = a00;
            mgT[(((size_t)i0 * 4 + qm) * 512 + dstb + 1) * 4 + jw] = a01;
            mgT[(((size_t)(i0 + 1) * 4 + qm) * 512 + dstb + 0) * 4 + jw] = a10;
            mgT[(((size_t)(i0 + 1) * 4 + qm) * 512 + dstb + 1) * 4 + jw] = a11;
        }
    }

    cg::this_grid().sync();

    // ==================== PHASE 2: attn + combine (R8 body) ====================
    {
        const int b   = xcd * 2 + (idx >> 4);   // same-XCD consumption
        const int tp  = idx & 15;
        const int d0a = tp * 32;
        const int b4  = b * 4;
        const int wave = t >> 6, L = t & 63, n = L & 15, q = L >> 4;
        const int io = wave >> 3;
        const int cv = (wave >> 2) & 1;
        const int h0 = (wave & 3) * 2;
        const int il = io * 2 + cv;
        const int inst = b4 + il;
        const int ij = il;

        const int ph = tp & 3;
        const int Pb = ph * 128;

        // stage Es/Fs for all 4 insts
        {
            const uint4* sE = (const uint4*)(sgEs + (size_t)b4 * 2048);
            const uint4* sF = (const uint4*)(sgFs + (size_t)b4 * 2048);
            uint4* dE = (uint4*)smem;
            uint4* dF = (uint4*)(smem + 8192);
            dE[t] = sE[t]; dE[1024 + t] = sE[1024 + t];
            dF[t] = sF[t]; dF[1024 + t] = sF[1024 + t];
        }

        unsigned int mwr[2][4];
        unsigned int iEd2[2][2], rd2[2][2];
#pragma unroll
        for (int tt = 0; tt < 2; ++tt) {
            const int d0 = d0a + tt * 16;
            const uint4 mreg =
                *(const uint4*)(mgT + (((size_t)inst * 4 + q) * 512 + d0 + n) * 4);
            const unsigned int mwt[4] = { mreg.x, mreg.y, mreg.z, mreg.w };
#pragma unroll
            for (int w = 0; w < 4; ++w) {       // mwr[w] = mwt[(w+ph)&3]
                const int src = (w + ph) & 3;
                unsigned int v = mwt[0];
                v = (src == 1) ? mwt[1] : v;
                v = (src == 2) ? mwt[2] : v;
                v = (src == 3) ? mwt[3] : v;
                mwr[tt][w] = v;
            }
#pragma unroll
            for (int hh = 0; hh < 2; ++hh) {
                const float2 ed = sgD[((size_t)inst * 8 + h0 + hh) * N_ + d0 + n];
                const float iEd = 1.0f / ed.x;
                const float rdv = ed.y * iEd;
                iEd2[tt][hh] = pkh(iEd, iEd);
                rd2[tt][hh] = pkh(rdv, rdv);
            }
        }

        __syncthreads();

        const unsigned short* xpi = xpt + (size_t)inst * D_ * N_;
        const unsigned short* bpq0 = xpi + (size_t)(h0 * 16 + n) * N_ + q * 8;
        const unsigned short* bpq1 = xpi + (size_t)((h0 + 1) * 16 + n) * N_ + q * 8;
        const unsigned int* esw = smem + il * 2048;
        const unsigned int* fsw = smem + 8192 + il * 2048;
        const unsigned int* e0p = esw + h0 * 256 + q * 4;
        const unsigned int* e1p = esw + (h0 + 1) * 256 + q * 4;
        const unsigned int* f0p = fsw + h0 * 256 + q * 4;
        const unsigned int* f1p = fsw + (h0 + 1) * 256 + q * 4;

        const uintx4 ou = { 0x3C003C00u, 0x3C003C00u, 0x3C003C00u, 0x3C003C00u };
        const half8 onesB = __builtin_bit_cast(half8, ou);

        floatx4 Cacc[2][2] = { { (floatx4){0.f,0.f,0.f,0.f}, (floatx4){0.f,0.f,0.f,0.f} },
                               { (floatx4){0.f,0.f,0.f,0.f}, (floatx4){0.f,0.f,0.f,0.f} } };
        floatx4 Cz[2][2]   = { { (floatx4){0.f,0.f,0.f,0.f}, (floatx4){0.f,0.f,0.f,0.f} },
                               { (floatx4){0.f,0.f,0.f,0.f}, (floatx4){0.f,0.f,0.f,0.f} } };

        uintx4 Bb0[4], Bb1[4];
#pragma unroll
        for (int c = 0; c < 4; ++c) {
            const int off = (c * 32 + Pb) & 511;
            Bb0[c] = *(const uintx4*)(bpq0 + off);
            Bb1[c] = *(const uintx4*)(bpq1 + off);
        }
#pragma unroll
        for (int c = 0; c < 16; ++c) {
            const int offe = (c * 16 + (Pb >> 1)) & 255;
#pragma unroll
            for (int hh = 0; hh < 2; ++hh) {
                const uint4 Ep = *(const uint4*)((hh ? e1p : e0p) + offe);
                const uint4 Fp = *(const uint4*)((hh ? f1p : f0p) + offe);
                const unsigned int eu[4] = { Ep.x, Ep.y, Ep.z, Ep.w };
                const unsigned int fu[4] = { Fp.x, Fp.y, Fp.z, Fp.w };
                const half8 Bc = __builtin_bit_cast(half8, hh ? Bb1[c & 3] : Bb0[c & 3]);
#pragma unroll
                for (int tt = 0; tt < 2; ++tt) {
                    const half2v rdh = __builtin_bit_cast(half2v, rd2[tt][hh]);
                    const unsigned int word = mwr[tt][c >> 2];
                    uintx4 au;
                    unsigned int wts[4];
#pragma unroll
                    for (int p = 0; p < 4; ++p) {
                        const int sh = (c & 3) * 8 + 2 * p;
                        const unsigned int wb2 = word >> sh;
                        const unsigned int sel =
                            ((wb2 & 1u) ? 0x0000FFFFu : 0u) |
                            ((wb2 & 2u) ? 0xFFFF0000u : 0u);
                        const half2v e = __builtin_bit_cast(half2v, eu[p]);
                        const half2v f = __builtin_bit_cast(half2v, fu[p]);
                        const half2v pr = f * rdh;
                        const half2v wv = __builtin_elementwise_max(pr, e);
                        const unsigned int wvu = __builtin_bit_cast(unsigned int, wv);
                        wts[p] = (sel & wvu) | (~sel & iEd2[tt][hh]);
                    }
                    au.x = wts[0]; au.y = wts[1]; au.z = wts[2]; au.w = wts[3];
                    const half8 As = __builtin_bit_cast(half8, au);
                    Cacc[tt][hh] = __builtin_amdgcn_mfma_f32_16x16x32_f16(
                        As, Bc, Cacc[tt][hh], 0, 0, 0);
                    Cz[tt][hh] = __builtin_amdgcn_mfma_f32_16x16x32_f16(
                        As, onesB, Cz[tt][hh], 0, 0, 0);
                }
            }
            if (c < 12) {
                const int off = ((c + 4) * 32 + Pb) & 511;
                Bb0[c & 3] = *(const uintx4*)(bpq0 + off);
                Bb1[c & 3] = *(const uintx4*)(bpq1 + off);
            }
        }

        // epilogue: this conv's full term per tile
        float vals[2][2][4];
#pragma unroll
        for (int tt = 0; tt < 2; ++tt) {
            const int d0 = d0a + tt * 16;
#pragma unroll
            for (int hh = 0; hh < 2; ++hh) {
                const int h = h0 + hh;
                const float bv = bias[ij * D_ + h * 16 + n];
                const uint2 sv =
                    *(const uint2*)(xpi + (size_t)(h * 16 + n) * N_ + d0 + q * 4);
                const half2v s0 = __builtin_bit_cast(half2v, sv.x);
                const half2v s1 = __builtin_bit_cast(half2v, sv.y);
                const float selfv[4] = { (float)s0[0], (float)s0[1],
                                         (float)s1[0], (float)s1[1] };
#pragma unroll
                for (int reg = 0; reg < 4; ++reg) {
                    const float Zi = 1.0f / Cz[tt][hh][reg];
                    vals[tt][hh][reg] = Cacc[tt][hh][reg] * Zi + selfv[reg] + bv;
                }
            }
        }

        __syncthreads();   // done reading es/fs -> alias out staging
        float* smf = (float*)smem;
        if (cv == 1) {
#pragma unroll
            for (int tt = 0; tt < 2; ++tt) {
                float* out_l = smf + (tt * 2 + io) * 2112;
#pragma unroll
                for (int hh = 0; hh < 2; ++hh)
#pragma unroll
                    for (int reg = 0; reg < 4; ++reg)
                        out_l[(q * 4 + reg) * 132 + (h0 + hh) * 16 + n] =
                            vals[tt][hh][reg];
            }
        }
        __syncthreads();
        if (cv == 0) {
#pragma unroll
            for (int tt = 0; tt < 2; ++tt) {
                float* out_l = smf + (tt * 2 + io) * 2112;
#pragma unroll
                for (int hh = 0; hh < 2; ++hh)
#pragma unroll
                    for (int reg = 0; reg < 4; ++reg) {
                        vals[tt][hh][reg] +=
                            out_l[(q * 4 + reg) * 132 + (h0 + hh) * 16 + n];
                        out_l[(q * 4 + reg) * 132 + (h0 + hh) * 16 + n] =
                            vals[tt][hh][reg];
                    }
            }
        }
        __syncthreads();
        if (cv == 0) {
#pragma unroll
            for (int tt = 0; tt < 2; ++tt) {
                const int d0 = d0a + tt * 16;
                const float* oth = smf + (tt * 2 + (1 - io)) * 2112;
#pragma unroll
                for (int hh = 0; hh < 2; ++hh)
#pragma unroll
                    for (int reg = 0; reg < 4; ++reg) {
                        const float other =
                            oth[(q * 4 + reg) * 132 + (h0 + hh) * 16 + n];
                        hout[((size_t)(b * 2 + io) * N_ + d0 + q * 4 + reg) * D_ +
                             (h0 + hh) * 16 + n] =
                            1.5f * vals[tt][hh][reg] + 0.5f * other;
                    }
            }
        }
    }
}

extern "C" void kernel_launch(void* const* d_in, const int* in_sizes, int n_in,
                              void* d_out, int out_size, void* d_ws, size_t ws_size,
                              hipStream_t stream)
{
    const float* x   = (const float*)d_in[0];
    const int*   A   = (const int*)d_in[1];
    const float* W   = (const float*)d_in[2];
    const float* pb  = (const float*)d_in[3];
    const float* as_ = (const float*)d_in[4];
    const float* ad_ = (const float*)d_in[5];
    const float* bs  = (const float*)d_in[6];

    unsigned short* xpt = (unsigned short*)d_ws;                              // 8 MB
    unsigned int* sgEs = (unsigned int*)((char*)d_ws + (8u << 20));           // 512 KB
    unsigned int* sgFs = (unsigned int*)((char*)d_ws + (8u << 20) + (512u << 10)); // 512 KB
    float2* sgD = (float2*)((char*)d_ws + (9u << 20));                        // 2 MB
    unsigned int* mgT = (unsigned int*)((char*)d_ws + (11u << 20));           // 2 MB
    float* h = (float*)d_out;

    void* args[13] = {
        (void*)&x, (void*)&W, (void*)&pb, (void*)&as_, (void*)&ad_,
        (void*)&A, (void*)&bs, (void*)&xpt, (void*)&sgEs, (void*)&sgFs,
        (void*)&sgD, (void*)&mgT, (void*)&h
    };
    (void)hipLaunchCooperativeKernel((void*)fused_kernel, dim3(256), dim3(1024),
                                     args, 0, stream);
}

// Round 10
// 134.349 us; speedup vs baseline: 1.3488x; 1.3488x over previous
//
#include <hip/hip_runtime.h>

#define N_ 512
#define D_ 128
#define LOG2E 1.44269504088896f

// ws: [0, 8 MB)        xp_t f16 TRANSPOSED [inst][f=128][s=512]      (8,388,608 B)
//     [8, 8.5 MB)      sgEs u32 [inst][h=8][sp=256]  (Es pairs f16)  (  524,288 B)
//     [8.5, 9 MB)      sgFs u32 [inst][h=8][sp=256]  (Fs pairs f16)  (  524,288 B)
//     [9, 11 MB)       sgD float2 [inst][h=8][s=512] (Ed, Fd fp32)   (2,097,152 B)
//     [11, 13 MB)      mgT u32 [inst][q=4][dst=512][jw=4]            (2,097,152 B)
// Factorized softmax: w = exp(leaky(ss+sd)) = max(Es*Ed, Fs*Fd); per-dst
// scale Ed cancels, K-loop uses w' = max(Es, Fs*rd) via PACKED f16 math.
// R10: REVERT of R9's cooperative fusion (regressed 132->181: 1-block/CU
// capped TLP, grid.sync killed cross-CU dispatch overlap, column-major A
// read uncoalesced). This is R8 (best: 132.4us) + T5 s_setprio bracketing
// each chunk's compute in attn (phase-staggered waves = the structure
// where setprio measured +4-7% on attention workloads).

typedef __attribute__((ext_vector_type(8))) short short8;
typedef __attribute__((ext_vector_type(4))) float floatx4;
typedef __attribute__((ext_vector_type(4))) unsigned int uintx4;
typedef __attribute__((ext_vector_type(2))) _Float16 half2v;
typedef __attribute__((ext_vector_type(8))) _Float16 half8;

#if defined(__has_builtin)
#if __has_builtin(__builtin_amdgcn_exp2f)
#define EXP2F(x) __builtin_amdgcn_exp2f(x)
#else
#define EXP2F(x) exp2f(x)
#endif
#else
#define EXP2F(x) exp2f(x)
#endif

// pack two f32 -> two f16 (v_cvt_pkrtz_f16_f32), low half = first arg.
__device__ __forceinline__ unsigned int pkh(float a, float b) {
    auto h = __builtin_amdgcn_cvt_pkrtz(a, b);
    return __builtin_bit_cast(unsigned int, h);
}

// ---------------------------------------------------------------------------
// Kernel 1 (fused prep): blocks 0..1023 = proj (f16 MFMA for xp + MFMA-based
// score reductions via va); blocks 1024..1535 = maskprep-T.  (R8-identical)
// ---------------------------------------------------------------------------
__global__ __launch_bounds__(256) void prep_kernel(
    const float* __restrict__ x, const float* __restrict__ W,
    const float* __restrict__ pb, const float* __restrict__ att_src,
    const float* __restrict__ att_dst, const int* __restrict__ A,
    unsigned short* __restrict__ xpt, unsigned int* __restrict__ sgEs,
    unsigned int* __restrict__ sgFs, float2* __restrict__ sgD,
    unsigned int* __restrict__ mgT)
{
    __shared__ _Float16 va_l[8][136];   // padded stride vs bank conflicts
    __shared__ float c0_l[8];

    const int bid0 = blockIdx.x;
    const int t = threadIdx.x;

    if (bid0 >= 1024) {
        // ---- maskprep-T: block = (bi, dstgroup of 128, s-range of 128) ----
        const int bid = bid0 - 1024;           // 0..511
        const int bi = bid >> 4;               // 0..31
        const int rem = bid & 15;
        const int dg = rem >> 2;               // dst group (128 each)
        const int jw = rem & 3;                // word index
        const int dp = t & 63, q = t >> 6;
        const int dstb = dg * 128 + dp * 2;
        const int sbase = jw * 128 + q * 8;
        const int* Ab = A + (size_t)bi * N_ * N_ + dstb;
        unsigned int a00 = 0, a01 = 0, a10 = 0, a11 = 0; // [conv][dd]
#pragma unroll
        for (int cp = 0; cp < 4; ++cp) {
#pragma unroll
            for (int i = 0; i < 8; ++i) {
                const int s = sbase + cp * 32 + i;
                const int2 v = *(const int2*)(Ab + (size_t)s * N_);
                const int bitp = cp * 8 + i;
                a00 |= ((0x14u >> v.x) & 1u) << bitp;   // val in {2,4}
                a10 |= ((0x18u >> v.x) & 1u) << bitp;   // val in {3,4}
                a01 |= ((0x14u >> v.y) & 1u) << bitp;
                a11 |= ((0x18u >> v.y) & 1u) << bitp;
            }
        }
        const int i0 = bi * 2;
        mgT[(((size_t)i0 * 4 + q) * 512 + dstb + 0) * 4 + jw] = a00;
        mgT[(((size_t)i0 * 4 + q) * 512 + dstb + 1) * 4 + jw] = a01;
        mgT[(((size_t)(i0 + 1) * 4 + q) * 512 + dstb + 0) * 4 + jw] = a10;
        mgT[(((size_t)(i0 + 1) * 4 + q) * 512 + dstb + 1) * 4 + jw] = a11;
        return;
    }

    // ------------- proj: 2 blocks per (inst, 64-row ntile) -------------
    const int unit = bid0 >> 1;
    const int half = bid0 & 1;
    const int ntile = unit & 7;
    const int inst  = unit >> 3;
    const int j = inst & 1;
    const int bi = inst >> 1;
    const int ij = (bi & 1) * 2 + j;
    const int wave = t >> 6, L = t & 63, n = L & 15, q = L >> 4;
    const float* wb = W + (size_t)ij * D_ * D_;

    // --- va pass: 256 threads build va[8][128] = LOG2E * (W_head^T a) ---
    {
        const int c = t >> 5;             // 0..7
        const int k0 = (t & 31) * 4;
        const int hn = half * 4 + (c & 3);
        const float* av = ((c < 4) ? att_src : att_dst) + ij * D_ + hn * 16;
        const float* Wh = wb + (size_t)(hn * 16) * D_ + k0;
        float a0 = 0.f, a1 = 0.f, a2 = 0.f, a3 = 0.f;
#pragma unroll
        for (int dd = 0; dd < 16; ++dd) {
            const float a = av[dd];
            const float4 wv = *(const float4*)(Wh + (size_t)dd * D_);
            a0 += wv.x * a; a1 += wv.y * a; a2 += wv.z * a; a3 += wv.w * a;
        }
        va_l[c][k0 + 0] = (_Float16)(a0 * LOG2E);
        va_l[c][k0 + 1] = (_Float16)(a1 * LOG2E);
        va_l[c][k0 + 2] = (_Float16)(a2 * LOG2E);
        va_l[c][k0 + 3] = (_Float16)(a3 * LOG2E);
        if (t < 8) {   // c0 = LOG2E * sum(pb * a) per c
            const int hn2 = half * 4 + (t & 3);
            const float* av2 = ((t < 4) ? att_src : att_dst) + ij * D_ + hn2 * 16;
            const float* pbp = pb + ij * D_ + hn2 * 16;
            float s = 0.f;
#pragma unroll
            for (int dd = 0; dd < 16; ++dd) s += pbp[dd] * av2[dd];
            c0_l[t] = s * LOG2E;
        }
    }

    const int n0w = ntile * 64 + wave * 16;
    const float* xrow = x + ((size_t)bi * N_ + n0w + n) * D_ + q * 8;
    half8 Af[4];
#pragma unroll
    for (int kc = 0; kc < 4; ++kc) {
        const float4 a0 = *(const float4*)(xrow + kc * 32);
        const float4 a1 = *(const float4*)(xrow + kc * 32 + 4);
        uintx4 au;
        au.x = pkh(a0.x, a0.y);
        au.y = pkh(a0.z, a0.w);
        au.z = pkh(a1.x, a1.y);
        au.w = pkh(a1.z, a1.w);
        Af[kc] = __builtin_bit_cast(half8, au);
    }

    __syncthreads();   // va_l ready

    // --- scores via MFMA: S[reg] = score[node n0w+q*4+reg][c=n] ---
    floatx4 S = (floatx4){0.f, 0.f, 0.f, 0.f};
    {
        const _Float16* var = &va_l[n & 7][q * 8];
#pragma unroll
        for (int kc = 0; kc < 4; ++kc) {
            const half8 Bs = *(const half8*)(var + kc * 32);
            S = __builtin_amdgcn_mfma_f32_16x16x32_f16(Af[kc], Bs, S, 0, 0, 0);
        }
    }

    // --- xp tiles ---
#pragma unroll
    for (int ft = 0; ft < 4; ++ft) {
        const int head = half * 4 + ft;
        const int fg = head * 16 + n;
        const float* wrow = wb + (size_t)fg * D_ + q * 8;
        floatx4 C = (floatx4){0.f, 0.f, 0.f, 0.f};
#pragma unroll
        for (int kc = 0; kc < 4; ++kc) {
            const float4 b0 = *(const float4*)(wrow + kc * 32);
            const float4 b1 = *(const float4*)(wrow + kc * 32 + 4);
            uintx4 bu;
            bu.x = pkh(b0.x, b0.y);
            bu.y = pkh(b0.z, b0.w);
            bu.z = pkh(b1.x, b1.y);
            bu.w = pkh(b1.z, b1.w);
            C = __builtin_amdgcn_mfma_f32_16x16x32_f16(
                Af[kc], __builtin_bit_cast(half8, bu), C, 0, 0, 0);
        }
        const float pbv = pb[ij * D_ + fg];
        uint2 pk;
        pk.x = pkh(C[0] + pbv, C[1] + pbv);
        pk.y = pkh(C[2] + pbv, C[3] + pbv);
        *(uint2*)&xpt[((size_t)inst * D_ + fg) * N_ + n0w + q * 4] = pk;
    }

    // --- score epilogue: lanes n<4 -> Es/Fs, lanes 4..7 -> Ed/Fd ---
    if (n < 8) {
        const float cc = c0_l[n];
        const float v0 = S[0] + cc, v1 = S[1] + cc;
        const float v2 = S[2] + cc, v3 = S[3] + cc;
        if (n < 4) {
            const int head = half * 4 + n;
            const size_t base = ((size_t)inst * 8 + head) * 256 + (n0w >> 1) + q * 2;
            sgEs[base + 0] = pkh(EXP2F(v0), EXP2F(v1));
            sgEs[base + 1] = pkh(EXP2F(v2), EXP2F(v3));
            sgFs[base + 0] = pkh(EXP2F(0.2f * v0), EXP2F(0.2f * v1));
            sgFs[base + 1] = pkh(EXP2F(0.2f * v2), EXP2F(0.2f * v3));
        } else {
            const int head = half * 4 + (n - 4);
            const size_t base = ((size_t)inst * 8 + head) * N_ + n0w + q * 4;
            float2 e0; e0.x = EXP2F(v0); e0.y = EXP2F(0.2f * v0); sgD[base + 0] = e0;
            float2 e1; e1.x = EXP2F(v1); e1.y = EXP2F(0.2f * v1); sgD[base + 1] = e1;
            float2 e2; e2.x = EXP2F(v2); e2.y = EXP2F(0.2f * v2); sgD[base + 2] = e2;
            float2 e3; e3.x = EXP2F(v3); e3.y = EXP2F(0.2f * v3); sgD[base + 3] = e3;
        }
    }
}

// ---------------------------------------------------------------------------
// Kernel 2: fused attention + combine, register-tiled T=2, phase-staggered.
// 256 blocks x 1024 threads; block = (b, tile-pair). xcd = bid&7 owns 2 b's.
// Chunk order a = (c + 4*(tp&3)) & 15 de-syncs phase groups (leader's L3
// fill becomes followers' L2 hit). Depth-4 B prefetch ring. T5 setprio
// brackets each chunk's compute (weight math + MFMA) vs prefetch refill.
// ---------------------------------------------------------------------------
__global__ __launch_bounds__(1024, 4) void attn_kernel(
    const unsigned short* __restrict__ xpt,
    const unsigned int* __restrict__ sgEs,
    const unsigned int* __restrict__ sgFs,
    const float2* __restrict__ sgD,
    const unsigned int* __restrict__ mgT,
    const float* __restrict__ bias,
    float* __restrict__ hout)
{
    __shared__ unsigned int smem[16384];    // es[4][2048] | fs at +8192; 64 KB

    const int bid = blockIdx.x;
    const int xcd = bid & 7;                // XCD (round-robin dispatch)
    const int idx = bid >> 3;               // 0..31 within XCD
    const int b   = xcd * 2 + (idx >> 4);   // 2 b per XCD -> L2-resident
    const int tp  = idx & 15;               // tile pair
    const int d0a = tp * 32;                // tiles d0a, d0a+16
    const int b4  = b * 4;
    const int t = threadIdx.x;
    const int wave = t >> 6, L = t & 63, n = L & 15, q = L >> 4;
    const int io = wave >> 3;               // order
    const int cv = (wave >> 2) & 1;         // conv
    const int h0 = (wave & 3) * 2;
    const int il = io * 2 + cv;             // inst_local 0..3
    const int inst = b4 + il;
    const int ij = il;                      // W/bias index == inst_local

    const int ph = tp & 3;                  // chunk phase group (x4 chunks)
    const int Pb = ph * 128;                // elem offset: (ph*4 chunks)*32

    // stage Es/Fs for all 4 insts (8192 u32 each stream)
    {
        const uint4* sE = (const uint4*)(sgEs + (size_t)b4 * 2048);
        const uint4* sF = (const uint4*)(sgFs + (size_t)b4 * 2048);
        uint4* dE = (uint4*)smem;
        uint4* dF = (uint4*)(smem + 8192);
        dE[t] = sE[t]; dE[1024 + t] = sE[1024 + t];
        dF[t] = sF[t]; dF[1024 + t] = sF[1024 + t];
    }

    // per-(tile,lane) mask bits (pre-rotated by phase) + dst factors
    unsigned int mwr[2][4];
    unsigned int iEd2[2][2], rd2[2][2];
#pragma unroll
    for (int tt = 0; tt < 2; ++tt) {
        const int d0 = d0a + tt * 16;
        const uint4 mreg =
            *(const uint4*)(mgT + (((size_t)inst * 4 + q) * 512 + d0 + n) * 4);
        const unsigned int mwt[4] = { mreg.x, mreg.y, mreg.z, mreg.w };
#pragma unroll
        for (int w = 0; w < 4; ++w) {       // mwr[w] = mwt[(w+ph)&3]
            const int src = (w + ph) & 3;
            unsigned int v = mwt[0];
            v = (src == 1) ? mwt[1] : v;
            v = (src == 2) ? mwt[2] : v;
            v = (src == 3) ? mwt[3] : v;
            mwr[tt][w] = v;
        }
#pragma unroll
        for (int hh = 0; hh < 2; ++hh) {
            const float2 ed = sgD[((size_t)inst * 8 + h0 + hh) * N_ + d0 + n];
            const float iEd = 1.0f / ed.x;
            const float rdv = ed.y * iEd;
            iEd2[tt][hh] = pkh(iEd, iEd);
            rd2[tt][hh] = pkh(rdv, rdv);
        }
    }

    __syncthreads();

    const unsigned short* xpi = xpt + (size_t)inst * D_ * N_;
    const unsigned short* bpq0 = xpi + (size_t)(h0 * 16 + n) * N_ + q * 8;
    const unsigned short* bpq1 = xpi + (size_t)((h0 + 1) * 16 + n) * N_ + q * 8;
    const unsigned int* esw = smem + il * 2048;
    const unsigned int* fsw = smem + 8192 + il * 2048;
    const unsigned int* e0p = esw + h0 * 256 + q * 4;
    const unsigned int* e1p = esw + (h0 + 1) * 256 + q * 4;
    const unsigned int* f0p = fsw + h0 * 256 + q * 4;
    const unsigned int* f1p = fsw + (h0 + 1) * 256 + q * 4;

    const uintx4 ou = { 0x3C003C00u, 0x3C003C00u, 0x3C003C00u, 0x3C003C00u };
    const half8 onesB = __builtin_bit_cast(half8, ou);

    floatx4 Cacc[2][2] = { { (floatx4){0.f,0.f,0.f,0.f}, (floatx4){0.f,0.f,0.f,0.f} },
                           { (floatx4){0.f,0.f,0.f,0.f}, (floatx4){0.f,0.f,0.f,0.f} } };
    floatx4 Cz[2][2]   = { { (floatx4){0.f,0.f,0.f,0.f}, (floatx4){0.f,0.f,0.f,0.f} },
                           { (floatx4){0.f,0.f,0.f,0.f}, (floatx4){0.f,0.f,0.f,0.f} } };

    // depth-4 prefetch ring over phase-rotated chunks
    uintx4 Bb0[4], Bb1[4];
#pragma unroll
    for (int c = 0; c < 4; ++c) {
        const int off = (c * 32 + Pb) & 511;
        Bb0[c] = *(const uintx4*)(bpq0 + off);
        Bb1[c] = *(const uintx4*)(bpq1 + off);
    }
#pragma unroll
    for (int c = 0; c < 16; ++c) {
        const int offe = (c * 16 + (Pb >> 1)) & 255;   // u32-pair offset
        __builtin_amdgcn_s_setprio(1);                 // T5: favor compute waves
#pragma unroll
        for (int hh = 0; hh < 2; ++hh) {
            const uint4 Ep = *(const uint4*)((hh ? e1p : e0p) + offe);
            const uint4 Fp = *(const uint4*)((hh ? f1p : f0p) + offe);
            const unsigned int eu[4] = { Ep.x, Ep.y, Ep.z, Ep.w };
            const unsigned int fu[4] = { Fp.x, Fp.y, Fp.z, Fp.w };
            const half8 Bc = __builtin_bit_cast(half8, hh ? Bb1[c & 3] : Bb0[c & 3]);
#pragma unroll
            for (int tt = 0; tt < 2; ++tt) {
                const half2v rdh = __builtin_bit_cast(half2v, rd2[tt][hh]);
                const unsigned int word = mwr[tt][c >> 2];
                uintx4 au;
                unsigned int wts[4];
#pragma unroll
                for (int p = 0; p < 4; ++p) {
                    const int sh = (c & 3) * 8 + 2 * p;  // compile-time constant
                    const unsigned int wb2 = word >> sh;
                    const unsigned int sel =
                        ((wb2 & 1u) ? 0x0000FFFFu : 0u) |
                        ((wb2 & 2u) ? 0xFFFF0000u : 0u);
                    const half2v e = __builtin_bit_cast(half2v, eu[p]);
                    const half2v f = __builtin_bit_cast(half2v, fu[p]);
                    const half2v pr = f * rdh;                          // v_pk_mul_f16
                    const half2v wv = __builtin_elementwise_max(pr, e); // v_pk_max_f16
                    const unsigned int wvu = __builtin_bit_cast(unsigned int, wv);
                    wts[p] = (sel & wvu) | (~sel & iEd2[tt][hh]);       // v_bfi
                }
                au.x = wts[0]; au.y = wts[1]; au.z = wts[2]; au.w = wts[3];
                const half8 As = __builtin_bit_cast(half8, au);
                Cacc[tt][hh] = __builtin_amdgcn_mfma_f32_16x16x32_f16(
                    As, Bc, Cacc[tt][hh], 0, 0, 0);
                Cz[tt][hh] = __builtin_amdgcn_mfma_f32_16x16x32_f16(
                    As, onesB, Cz[tt][hh], 0, 0, 0);
            }
        }
        __builtin_amdgcn_s_setprio(0);                 // refill at low prio
        if (c < 12) {   // refill ring slot with chunk c+4 (rotated)
            const int off = ((c + 4) * 32 + Pb) & 511;
            Bb0[c & 3] = *(const uintx4*)(bpq0 + off);
            Bb1[c & 3] = *(const uintx4*)(bpq1 + off);
        }
    }

    // epilogue: this conv's full term per tile (Ed cancels in ratio)
    float vals[2][2][4];   // [tt][hh][reg]
#pragma unroll
    for (int tt = 0; tt < 2; ++tt) {
        const int d0 = d0a + tt * 16;
#pragma unroll
        for (int hh = 0; hh < 2; ++hh) {
            const int h = h0 + hh;
            const float bv = bias[ij * D_ + h * 16 + n];
            const uint2 sv =
                *(const uint2*)(xpi + (size_t)(h * 16 + n) * N_ + d0 + q * 4);
            const half2v s0 = __builtin_bit_cast(half2v, sv.x);
            const half2v s1 = __builtin_bit_cast(half2v, sv.y);
            const float selfv[4] = { (float)s0[0], (float)s0[1],
                                     (float)s1[0], (float)s1[1] };
#pragma unroll
            for (int reg = 0; reg < 4; ++reg) {
                const float Zi = 1.0f / Cz[tt][hh][reg];
                vals[tt][hh][reg] = Cacc[tt][hh][reg] * Zi + selfv[reg] + bv;
            }
        }
    }

    __syncthreads();   // all waves done reading es/fs -> alias out staging
    // out staging: [tt][order io]: floats at (tt*2+io)*2112, layout
    // [dst 16][feat 128] stride 132 (pad).
    float* smf = (float*)smem;
    if (cv == 1) {     // deposit conv-1 term
#pragma unroll
        for (int tt = 0; tt < 2; ++tt) {
            float* out_l = smf + (tt * 2 + io) * 2112;
#pragma unroll
            for (int hh = 0; hh < 2; ++hh)
#pragma unroll
                for (int reg = 0; reg < 4; ++reg)
                    out_l[(q * 4 + reg) * 132 + (h0 + hh) * 16 + n] =
                        vals[tt][hh][reg];
        }
    }
    __syncthreads();
    if (cv == 0) {     // h_i = conv0 + conv1; write back for cross-order mix
#pragma unroll
        for (int tt = 0; tt < 2; ++tt) {
            float* out_l = smf + (tt * 2 + io) * 2112;
#pragma unroll
            for (int hh = 0; hh < 2; ++hh)
#pragma unroll
                for (int reg = 0; reg < 4; ++reg) {
                    vals[tt][hh][reg] +=
                        out_l[(q * 4 + reg) * 132 + (h0 + hh) * 16 + n];
                    out_l[(q * 4 + reg) * 132 + (h0 + hh) * 16 + n] =
                        vals[tt][hh][reg];
                }
        }
    }
    __syncthreads();
    if (cv == 0) {     // out[b,i] = 1.5 h_i + 0.5 h_{1-i}
#pragma unroll
        for (int tt = 0; tt < 2; ++tt) {
            const int d0 = d0a + tt * 16;
            const float* oth = smf + (tt * 2 + (1 - io)) * 2112;
#pragma unroll
            for (int hh = 0; hh < 2; ++hh)
#pragma unroll
                for (int reg = 0; reg < 4; ++reg) {
                    const float other =
                        oth[(q * 4 + reg) * 132 + (h0 + hh) * 16 + n];
                    hout[((size_t)(b * 2 + io) * N_ + d0 + q * 4 + reg) * D_ +
                         (h0 + hh) * 16 + n] =
                        1.5f * vals[tt][hh][reg] + 0.5f * other;
                }
        }
    }
}

extern "C" void kernel_launch(void* const* d_in, const int* in_sizes, int n_in,
                              void* d_out, int out_size, void* d_ws, size_t ws_size,
                              hipStream_t stream)
{
    const float* x   = (const float*)d_in[0];
    const int*   A   = (const int*)d_in[1];
    const float* W   = (const float*)d_in[2];
    const float* pb  = (const float*)d_in[3];
    const float* as_ = (const float*)d_in[4];
    const float* ad_ = (const float*)d_in[5];
    const float* bs  = (const float*)d_in[6];

    unsigned short* xpt = (unsigned short*)d_ws;                              // 8 MB
    unsigned int* sgEs = (unsigned int*)((char*)d_ws + (8u << 20));           // 512 KB
    unsigned int* sgFs = (unsigned int*)((char*)d_ws + (8u << 20) + (512u << 10)); // 512 KB
    float2* sgD = (float2*)((char*)d_ws + (9u << 20));                        // 2 MB
    unsigned int* mgT = (unsigned int*)((char*)d_ws + (11u << 20));           // 2 MB
    float* h = (float*)d_out;

    prep_kernel<<<1536, 256, 0, stream>>>(x, W, pb, as_, ad_, A, xpt, sgEs, sgFs, sgD, mgT);
    attn_kernel<<<256, 1024, 0, stream>>>(xpt, sgEs, sgFs, sgD, mgT, bs, h);
}

// Round 11
// 131.744 us; speedup vs baseline: 1.3754x; 1.0198x over previous
//
#include <hip/hip_runtime.h>

#define N_ 512
#define D_ 128
#define LOG2E 1.44269504088896f

// ws: [0, 8 MB)        xp_t f16 TRANSPOSED [inst][f=128][s=512]      (8,388,608 B)
//     [8, 8.5 MB)      sgEs u32 [inst][h=8][sp=256]  (Es pairs f16)  (  524,288 B)
//     [8.5, 9 MB)      sgFs u32 [inst][h=8][sp=256]  (Fs pairs f16)  (  524,288 B)
//     [9, 11 MB)       sgD float2 [inst][h=8][s=512] (Ed, Fd fp32)   (2,097,152 B)
//     [11, 13 MB)      mgT u32 [inst][q=4][dst=512][jw=4]            (2,097,152 B)
// Factorized softmax: w = exp(leaky(ss+sd)) = max(Es*Ed, Fs*Fd); per-dst
// scale Ed cancels, K-loop uses w' = max(Es, Fs*rd) via PACKED f16 math.
// R11: exact revert to R8 (best measured: 132.4us). R9 coop-fusion
// regressed (-49us: TLP cap + lost dispatch overlap); R10 setprio
// regressed (-1.9us: 1-block/CU lockstep waves = the m190 null case).
// Session conclusion: ~87us/iter is harness workspace re-poison; the
// ~45us controllable part is latency-bound at its structural floor.

typedef __attribute__((ext_vector_type(8))) short short8;
typedef __attribute__((ext_vector_type(4))) float floatx4;
typedef __attribute__((ext_vector_type(4))) unsigned int uintx4;
typedef __attribute__((ext_vector_type(2))) _Float16 half2v;
typedef __attribute__((ext_vector_type(8))) _Float16 half8;

#if defined(__has_builtin)
#if __has_builtin(__builtin_amdgcn_exp2f)
#define EXP2F(x) __builtin_amdgcn_exp2f(x)
#else
#define EXP2F(x) exp2f(x)
#endif
#else
#define EXP2F(x) exp2f(x)
#endif

// pack two f32 -> two f16 (v_cvt_pkrtz_f16_f32), low half = first arg.
__device__ __forceinline__ unsigned int pkh(float a, float b) {
    auto h = __builtin_amdgcn_cvt_pkrtz(a, b);
    return __builtin_bit_cast(unsigned int, h);
}

// ---------------------------------------------------------------------------
// Kernel 1 (fused prep): blocks 0..1023 = proj (f16 MFMA for xp + MFMA-based
// score reductions via va); blocks 1024..1535 = maskprep-T.
// ---------------------------------------------------------------------------
__global__ __launch_bounds__(256) void prep_kernel(
    const float* __restrict__ x, const float* __restrict__ W,
    const float* __restrict__ pb, const float* __restrict__ att_src,
    const float* __restrict__ att_dst, const int* __restrict__ A,
    unsigned short* __restrict__ xpt, unsigned int* __restrict__ sgEs,
    unsigned int* __restrict__ sgFs, float2* __restrict__ sgD,
    unsigned int* __restrict__ mgT)
{
    __shared__ _Float16 va_l[8][136];   // padded stride vs bank conflicts
    __shared__ float c0_l[8];

    const int bid0 = blockIdx.x;
    const int t = threadIdx.x;

    if (bid0 >= 1024) {
        // ---- maskprep-T: block = (bi, dstgroup of 128, s-range of 128) ----
        const int bid = bid0 - 1024;           // 0..511
        const int bi = bid >> 4;               // 0..31
        const int rem = bid & 15;
        const int dg = rem >> 2;               // dst group (128 each)
        const int jw = rem & 3;                // word index
        const int dp = t & 63, q = t >> 6;
        const int dstb = dg * 128 + dp * 2;
        const int sbase = jw * 128 + q * 8;
        const int* Ab = A + (size_t)bi * N_ * N_ + dstb;
        unsigned int a00 = 0, a01 = 0, a10 = 0, a11 = 0; // [conv][dd]
#pragma unroll
        for (int cp = 0; cp < 4; ++cp) {
#pragma unroll
            for (int i = 0; i < 8; ++i) {
                const int s = sbase + cp * 32 + i;
                const int2 v = *(const int2*)(Ab + (size_t)s * N_);
                const int bitp = cp * 8 + i;
                a00 |= ((0x14u >> v.x) & 1u) << bitp;   // val in {2,4}
                a10 |= ((0x18u >> v.x) & 1u) << bitp;   // val in {3,4}
                a01 |= ((0x14u >> v.y) & 1u) << bitp;
                a11 |= ((0x18u >> v.y) & 1u) << bitp;
            }
        }
        const int i0 = bi * 2;
        mgT[(((size_t)i0 * 4 + q) * 512 + dstb + 0) * 4 + jw] = a00;
        mgT[(((size_t)i0 * 4 + q) * 512 + dstb + 1) * 4 + jw] = a01;
        mgT[(((size_t)(i0 + 1) * 4 + q) * 512 + dstb + 0) * 4 + jw] = a10;
        mgT[(((size_t)(i0 + 1) * 4 + q) * 512 + dstb + 1) * 4 + jw] = a11;
        return;
    }

    // ------------- proj: 2 blocks per (inst, 64-row ntile) -------------
    const int unit = bid0 >> 1;
    const int half = bid0 & 1;
    const int ntile = unit & 7;
    const int inst  = unit >> 3;
    const int j = inst & 1;
    const int bi = inst >> 1;
    const int ij = (bi & 1) * 2 + j;
    const int wave = t >> 6, L = t & 63, n = L & 15, q = L >> 4;
    const float* wb = W + (size_t)ij * D_ * D_;

    // --- va pass: 256 threads build va[8][128] = LOG2E * (W_head^T a) ---
    {
        const int c = t >> 5;             // 0..7
        const int k0 = (t & 31) * 4;
        const int hn = half * 4 + (c & 3);
        const float* av = ((c < 4) ? att_src : att_dst) + ij * D_ + hn * 16;
        const float* Wh = wb + (size_t)(hn * 16) * D_ + k0;
        float a0 = 0.f, a1 = 0.f, a2 = 0.f, a3 = 0.f;
#pragma unroll
        for (int dd = 0; dd < 16; ++dd) {
            const float a = av[dd];
            const float4 wv = *(const float4*)(Wh + (size_t)dd * D_);
            a0 += wv.x * a; a1 += wv.y * a; a2 += wv.z * a; a3 += wv.w * a;
        }
        va_l[c][k0 + 0] = (_Float16)(a0 * LOG2E);
        va_l[c][k0 + 1] = (_Float16)(a1 * LOG2E);
        va_l[c][k0 + 2] = (_Float16)(a2 * LOG2E);
        va_l[c][k0 + 3] = (_Float16)(a3 * LOG2E);
        if (t < 8) {   // c0 = LOG2E * sum(pb * a) per c
            const int hn2 = half * 4 + (t & 3);
            const float* av2 = ((t < 4) ? att_src : att_dst) + ij * D_ + hn2 * 16;
            const float* pbp = pb + ij * D_ + hn2 * 16;
            float s = 0.f;
#pragma unroll
            for (int dd = 0; dd < 16; ++dd) s += pbp[dd] * av2[dd];
            c0_l[t] = s * LOG2E;
        }
    }

    const int n0w = ntile * 64 + wave * 16;
    const float* xrow = x + ((size_t)bi * N_ + n0w + n) * D_ + q * 8;
    half8 Af[4];
#pragma unroll
    for (int kc = 0; kc < 4; ++kc) {
        const float4 a0 = *(const float4*)(xrow + kc * 32);
        const float4 a1 = *(const float4*)(xrow + kc * 32 + 4);
        uintx4 au;
        au.x = pkh(a0.x, a0.y);
        au.y = pkh(a0.z, a0.w);
        au.z = pkh(a1.x, a1.y);
        au.w = pkh(a1.z, a1.w);
        Af[kc] = __builtin_bit_cast(half8, au);
    }

    __syncthreads();   // va_l ready

    // --- scores via MFMA: S[reg] = score[node n0w+q*4+reg][c=n] ---
    floatx4 S = (floatx4){0.f, 0.f, 0.f, 0.f};
    {
        const _Float16* var = &va_l[n & 7][q * 8];
#pragma unroll
        for (int kc = 0; kc < 4; ++kc) {
            const half8 Bs = *(const half8*)(var + kc * 32);
            S = __builtin_amdgcn_mfma_f32_16x16x32_f16(Af[kc], Bs, S, 0, 0, 0);
        }
    }

    // --- xp tiles ---
#pragma unroll
    for (int ft = 0; ft < 4; ++ft) {
        const int head = half * 4 + ft;
        const int fg = head * 16 + n;
        const float* wrow = wb + (size_t)fg * D_ + q * 8;
        floatx4 C = (floatx4){0.f, 0.f, 0.f, 0.f};
#pragma unroll
        for (int kc = 0; kc < 4; ++kc) {
            const float4 b0 = *(const float4*)(wrow + kc * 32);
            const float4 b1 = *(const float4*)(wrow + kc * 32 + 4);
            uintx4 bu;
            bu.x = pkh(b0.x, b0.y);
            bu.y = pkh(b0.z, b0.w);
            bu.z = pkh(b1.x, b1.y);
            bu.w = pkh(b1.z, b1.w);
            C = __builtin_amdgcn_mfma_f32_16x16x32_f16(
                Af[kc], __builtin_bit_cast(half8, bu), C, 0, 0, 0);
        }
        const float pbv = pb[ij * D_ + fg];
        uint2 pk;
        pk.x = pkh(C[0] + pbv, C[1] + pbv);
        pk.y = pkh(C[2] + pbv, C[3] + pbv);
        *(uint2*)&xpt[((size_t)inst * D_ + fg) * N_ + n0w + q * 4] = pk;
    }

    // --- score epilogue: lanes n<4 -> Es/Fs, lanes 4..7 -> Ed/Fd ---
    if (n < 8) {
        const float cc = c0_l[n];
        const float v0 = S[0] + cc, v1 = S[1] + cc;
        const float v2 = S[2] + cc, v3 = S[3] + cc;
        if (n < 4) {
            const int head = half * 4 + n;
            const size_t base = ((size_t)inst * 8 + head) * 256 + (n0w >> 1) + q * 2;
            sgEs[base + 0] = pkh(EXP2F(v0), EXP2F(v1));
            sgEs[base + 1] = pkh(EXP2F(v2), EXP2F(v3));
            sgFs[base + 0] = pkh(EXP2F(0.2f * v0), EXP2F(0.2f * v1));
            sgFs[base + 1] = pkh(EXP2F(0.2f * v2), EXP2F(0.2f * v3));
        } else {
            const int head = half * 4 + (n - 4);
            const size_t base = ((size_t)inst * 8 + head) * N_ + n0w + q * 4;
            float2 e0; e0.x = EXP2F(v0); e0.y = EXP2F(0.2f * v0); sgD[base + 0] = e0;
            float2 e1; e1.x = EXP2F(v1); e1.y = EXP2F(0.2f * v1); sgD[base + 1] = e1;
            float2 e2; e2.x = EXP2F(v2); e2.y = EXP2F(0.2f * v2); sgD[base + 2] = e2;
            float2 e3; e3.x = EXP2F(v3); e3.y = EXP2F(0.2f * v3); sgD[base + 3] = e3;
        }
    }
}

// ---------------------------------------------------------------------------
// Kernel 2: fused attention + combine, register-tiled T=2, phase-staggered.
// 256 blocks x 1024 threads; block = (b, tile-pair). xcd = bid&7 owns 2 b's.
// Chunk processing order a = (c + 4*(tp&3)) & 15: phase groups de-sync so
// the leader's L3 fill becomes everyone else's L2 hit. Depth-4 B prefetch
// ring. Masks pre-rotated by phase via 4:1 muxes (all reg indices static).
// ---------------------------------------------------------------------------
__global__ __launch_bounds__(1024, 4) void attn_kernel(
    const unsigned short* __restrict__ xpt,
    const unsigned int* __restrict__ sgEs,
    const unsigned int* __restrict__ sgFs,
    const float2* __restrict__ sgD,
    const unsigned int* __restrict__ mgT,
    const float* __restrict__ bias,
    float* __restrict__ hout)
{
    __shared__ unsigned int smem[16384];    // es[4][2048] | fs at +8192; 64 KB

    const int bid = blockIdx.x;
    const int xcd = bid & 7;                // XCD (round-robin dispatch)
    const int idx = bid >> 3;               // 0..31 within XCD
    const int b   = xcd * 2 + (idx >> 4);   // 2 b per XCD -> L2-resident
    const int tp  = idx & 15;               // tile pair
    const int d0a = tp * 32;                // tiles d0a, d0a+16
    const int b4  = b * 4;
    const int t = threadIdx.x;
    const int wave = t >> 6, L = t & 63, n = L & 15, q = L >> 4;
    const int io = wave >> 3;               // order
    const int cv = (wave >> 2) & 1;         // conv
    const int h0 = (wave & 3) * 2;
    const int il = io * 2 + cv;             // inst_local 0..3
    const int inst = b4 + il;
    const int ij = il;                      // W/bias index == inst_local

    const int ph = tp & 3;                  // chunk phase group (x4 chunks)
    const int Pb = ph * 128;                // elem offset: (ph*4 chunks)*32

    // stage Es/Fs for all 4 insts (8192 u32 each stream)
    {
        const uint4* sE = (const uint4*)(sgEs + (size_t)b4 * 2048);
        const uint4* sF = (const uint4*)(sgFs + (size_t)b4 * 2048);
        uint4* dE = (uint4*)smem;
        uint4* dF = (uint4*)(smem + 8192);
        dE[t] = sE[t]; dE[1024 + t] = sE[1024 + t];
        dF[t] = sF[t]; dF[1024 + t] = sF[1024 + t];
    }

    // per-(tile,lane) mask bits (pre-rotated by phase) + dst factors
    unsigned int mwr[2][4];
    unsigned int iEd2[2][2], rd2[2][2];
#pragma unroll
    for (int tt = 0; tt < 2; ++tt) {
        const int d0 = d0a + tt * 16;
        const uint4 mreg =
            *(const uint4*)(mgT + (((size_t)inst * 4 + q) * 512 + d0 + n) * 4);
        const unsigned int mwt[4] = { mreg.x, mreg.y, mreg.z, mreg.w };
#pragma unroll
        for (int w = 0; w < 4; ++w) {       // mwr[w] = mwt[(w+ph)&3]
            const int src = (w + ph) & 3;
            unsigned int v = mwt[0];
            v = (src == 1) ? mwt[1] : v;
            v = (src == 2) ? mwt[2] : v;
            v = (src == 3) ? mwt[3] : v;
            mwr[tt][w] = v;
        }
#pragma unroll
        for (int hh = 0; hh < 2; ++hh) {
            const float2 ed = sgD[((size_t)inst * 8 + h0 + hh) * N_ + d0 + n];
            const float iEd = 1.0f / ed.x;
            const float rdv = ed.y * iEd;
            iEd2[tt][hh] = pkh(iEd, iEd);
            rd2[tt][hh] = pkh(rdv, rdv);
        }
    }

    __syncthreads();

    const unsigned short* xpi = xpt + (size_t)inst * D_ * N_;
    const unsigned short* bpq0 = xpi + (size_t)(h0 * 16 + n) * N_ + q * 8;
    const unsigned short* bpq1 = xpi + (size_t)((h0 + 1) * 16 + n) * N_ + q * 8;
    const unsigned int* esw = smem + il * 2048;
    const unsigned int* fsw = smem + 8192 + il * 2048;
    const unsigned int* e0p = esw + h0 * 256 + q * 4;
    const unsigned int* e1p = esw + (h0 + 1) * 256 + q * 4;
    const unsigned int* f0p = fsw + h0 * 256 + q * 4;
    const unsigned int* f1p = fsw + (h0 + 1) * 256 + q * 4;

    const uintx4 ou = { 0x3C003C00u, 0x3C003C00u, 0x3C003C00u, 0x3C003C00u };
    const half8 onesB = __builtin_bit_cast(half8, ou);

    floatx4 Cacc[2][2] = { { (floatx4){0.f,0.f,0.f,0.f}, (floatx4){0.f,0.f,0.f,0.f} },
                           { (floatx4){0.f,0.f,0.f,0.f}, (floatx4){0.f,0.f,0.f,0.f} } };
    floatx4 Cz[2][2]   = { { (floatx4){0.f,0.f,0.f,0.f}, (floatx4){0.f,0.f,0.f,0.f} },
                           { (floatx4){0.f,0.f,0.f,0.f}, (floatx4){0.f,0.f,0.f,0.f} } };

    // depth-4 prefetch ring over phase-rotated chunks
    uintx4 Bb0[4], Bb1[4];
#pragma unroll
    for (int c = 0; c < 4; ++c) {
        const int off = (c * 32 + Pb) & 511;
        Bb0[c] = *(const uintx4*)(bpq0 + off);
        Bb1[c] = *(const uintx4*)(bpq1 + off);
    }
#pragma unroll
    for (int c = 0; c < 16; ++c) {
        const int offe = (c * 16 + (Pb >> 1)) & 255;   // u32-pair offset
#pragma unroll
        for (int hh = 0; hh < 2; ++hh) {
            const uint4 Ep = *(const uint4*)((hh ? e1p : e0p) + offe);
            const uint4 Fp = *(const uint4*)((hh ? f1p : f0p) + offe);
            const unsigned int eu[4] = { Ep.x, Ep.y, Ep.z, Ep.w };
            const unsigned int fu[4] = { Fp.x, Fp.y, Fp.z, Fp.w };
            const half8 Bc = __builtin_bit_cast(half8, hh ? Bb1[c & 3] : Bb0[c & 3]);
#pragma unroll
            for (int tt = 0; tt < 2; ++tt) {
                const half2v rdh = __builtin_bit_cast(half2v, rd2[tt][hh]);
                const unsigned int word = mwr[tt][c >> 2];
                uintx4 au;
                unsigned int wts[4];
#pragma unroll
                for (int p = 0; p < 4; ++p) {
                    const int sh = (c & 3) * 8 + 2 * p;  // compile-time constant
                    const unsigned int wb2 = word >> sh;
                    const unsigned int sel =
                        ((wb2 & 1u) ? 0x0000FFFFu : 0u) |
                        ((wb2 & 2u) ? 0xFFFF0000u : 0u);
                    const half2v e = __builtin_bit_cast(half2v, eu[p]);
                    const half2v f = __builtin_bit_cast(half2v, fu[p]);
                    const half2v pr = f * rdh;                          // v_pk_mul_f16
                    const half2v wv = __builtin_elementwise_max(pr, e); // v_pk_max_f16
                    const unsigned int wvu = __builtin_bit_cast(unsigned int, wv);
                    wts[p] = (sel & wvu) | (~sel & iEd2[tt][hh]);       // v_bfi
                }
                au.x = wts[0]; au.y = wts[1]; au.z = wts[2]; au.w = wts[3];
                const half8 As = __builtin_bit_cast(half8, au);
                Cacc[tt][hh] = __builtin_amdgcn_mfma_f32_16x16x32_f16(
                    As, Bc, Cacc[tt][hh], 0, 0, 0);
                Cz[tt][hh] = __builtin_amdgcn_mfma_f32_16x16x32_f16(
                    As, onesB, Cz[tt][hh], 0, 0, 0);
            }
        }
        if (c < 12) {   // refill ring slot with chunk c+4 (rotated)
            const int off = ((c + 4) * 32 + Pb) & 511;
            Bb0[c & 3] = *(const uintx4*)(bpq0 + off);
            Bb1[c & 3] = *(const uintx4*)(bpq1 + off);
        }
    }

    // epilogue: this conv's full term per tile (Ed cancels in ratio)
    float vals[2][2][4];   // [tt][hh][reg]
#pragma unroll
    for (int tt = 0; tt < 2; ++tt) {
        const int d0 = d0a + tt * 16;
#pragma unroll
        for (int hh = 0; hh < 2; ++hh) {
            const int h = h0 + hh;
            const float bv = bias[ij * D_ + h * 16 + n];
            const uint2 sv =
                *(const uint2*)(xpi + (size_t)(h * 16 + n) * N_ + d0 + q * 4);
            const half2v s0 = __builtin_bit_cast(half2v, sv.x);
            const half2v s1 = __builtin_bit_cast(half2v, sv.y);
            const float selfv[4] = { (float)s0[0], (float)s0[1],
                                     (float)s1[0], (float)s1[1] };
#pragma unroll
            for (int reg = 0; reg < 4; ++reg) {
                const float Zi = 1.0f / Cz[tt][hh][reg];
                vals[tt][hh][reg] = Cacc[tt][hh][reg] * Zi + selfv[reg] + bv;
            }
        }
    }

    __syncthreads();   // all waves done reading es/fs -> alias out staging
    // out staging: [tt][order io]: floats at (tt*2+io)*2112, layout
    // [dst 16][feat 128] stride 132 (pad).
    float* smf = (float*)smem;
    if (cv == 1) {     // deposit conv-1 term
#pragma unroll
        for (int tt = 0; tt < 2; ++tt) {
            float* out_l = smf + (tt * 2 + io) * 2112;
#pragma unroll
            for (int hh = 0; hh < 2; ++hh)
#pragma unroll
                for (int reg = 0; reg < 4; ++reg)
                    out_l[(q * 4 + reg) * 132 + (h0 + hh) * 16 + n] =
                        vals[tt][hh][reg];
        }
    }
    __syncthreads();
    if (cv == 0) {     // h_i = conv0 + conv1; write back for cross-order mix
#pragma unroll
        for (int tt = 0; tt < 2; ++tt) {
            float* out_l = smf + (tt * 2 + io) * 2112;
#pragma unroll
            for (int hh = 0; hh < 2; ++hh)
#pragma unroll
                for (int reg = 0; reg < 4; ++reg) {
                    vals[tt][hh][reg] +=
                        out_l[(q * 4 + reg) * 132 + (h0 + hh) * 16 + n];
                    out_l[(q * 4 + reg) * 132 + (h0 + hh) * 16 + n] =
                        vals[tt][hh][reg];
                }
        }
    }
    __syncthreads();
    if (cv == 0) {     // out[b,i] = 1.5 h_i + 0.5 h_{1-i}
#pragma unroll
        for (int tt = 0; tt < 2; ++tt) {
            const int d0 = d0a + tt * 16;
            const float* oth = smf + (tt * 2 + (1 - io)) * 2112;
#pragma unroll
            for (int hh = 0; hh < 2; ++hh)
#pragma unroll
                for (int reg = 0; reg < 4; ++reg) {
                    const float other =
                        oth[(q * 4 + reg) * 132 + (h0 + hh) * 16 + n];
                    hout[((size_t)(b * 2 + io) * N_ + d0 + q * 4 + reg) * D_ +
                         (h0 + hh) * 16 + n] =
                        1.5f * vals[tt][hh][reg] + 0.5f * other;
                }
        }
    }
}

extern "C" void kernel_launch(void* const* d_in, const int* in_sizes, int n_in,
                              void* d_out, int out_size, void* d_ws, size_t ws_size,
                              hipStream_t stream)
{
    const float* x   = (const float*)d_in[0];
    const int*   A   = (const int*)d_in[1];
    const float* W   = (const float*)d_in[2];
    const float* pb  = (const float*)d_in[3];
    const float* as_ = (const float*)d_in[4];
    const float* ad_ = (const float*)d_in[5];
    const float* bs  = (const float*)d_in[6];

    unsigned short* xpt = (unsigned short*)d_ws;                              // 8 MB
    unsigned int* sgEs = (unsigned int*)((char*)d_ws + (8u << 20));           // 512 KB
    unsigned int* sgFs = (unsigned int*)((char*)d_ws + (8u << 20) + (512u << 10)); // 512 KB
    float2* sgD = (float2*)((char*)d_ws + (9u << 20));                        // 2 MB
    unsigned int* mgT = (unsigned int*)((char*)d_ws + (11u << 20));           // 2 MB
    float* h = (float*)d_out;

    prep_kernel<<<1536, 256, 0, stream>>>(x, W, pb, as_, ad_, A, xpt, sgEs, sgFs, sgD, mgT);
    attn_kernel<<<256, 1024, 0, stream>>>(xpt, sgEs, sgFs, sgD, mgT, bs, h);
}